// Round 12
// baseline (419.455 us; speedup 1.0000x reference)
//
#include <hip/hip_runtime.h>
#include <hip/hip_cooperative_groups.h>
#include <math.h>

namespace cg = cooperative_groups;

#define BB 1024
#define SS 50
#define SSP 51          // padded LDS row stride for shT
#define HH 128
#define KK 4
#define VV 100000
#define NVT 782         // ceil(V/128)
#define NVT8 784        // padded to multiple of 8 for XCD swizzle
#define VPAD (NVT8*128) // 100352 zero-padded emb rows
#define KS (KK*SS)      // 200
#define NHM 400         // h-MFMA blocks (128 rows each)
#define NPAD_LAST 96.0f // pad rows in tile 781, each contributes exp(0)=1

typedef __attribute__((ext_vector_type(8))) short bf16x8;
typedef __attribute__((ext_vector_type(4))) float f32x4;

__device__ __forceinline__ ushort f2bf(float x) {
  unsigned u = __float_as_uint(x);
  unsigned r = u + 0x7FFF + ((u >> 16) & 1);   // round-to-nearest-even
  return (ushort)(r >> 16);
}
__device__ __forceinline__ float bf2f(ushort u) {
  return __uint_as_float(((unsigned)u) << 16);
}
__device__ __forceinline__ bf16x8 cvt8(float4 a, float4 b) {
  bf16x8 r;
  r[0] = (short)f2bf(a.x); r[1] = (short)f2bf(a.y);
  r[2] = (short)f2bf(a.z); r[3] = (short)f2bf(a.w);
  r[4] = (short)f2bf(b.x); r[5] = (short)f2bf(b.y);
  r[6] = (short)f2bf(b.z); r[7] = (short)f2bf(b.w);
  return r;
}

// ---- standalone emb -> bf16 conversion (ZERO LDS -> full occupancy BW) ---
__global__ __launch_bounds__(256) void k_conv(const float* __restrict__ emb,
                                              ushort* __restrict__ embb) {
  size_t i = ((size_t)blockIdx.x * 256 + threadIdx.x) * 4;
  ushort4 o;
  if (i < (size_t)VV * HH) {
    float4 v = *(const float4*)&emb[i];
    o = make_ushort4(f2bf(v.x), f2bf(v.y), f2bf(v.z), f2bf(v.w));
  } else {
    o = make_ushort4(0, 0, 0, 0);
  }
  *(ushort4*)&embb[i] = o;
}

// ---- fused pre-pass ------------------------------------------------------
// blocks [0,NHM): h = seq_emb @ W^T via bf16 MFMA -> hb16
// blocks [NHM,NHM+KS): cw0 column exp-sums + zero s1/s2/accum
__global__ __launch_bounds__(256) void k_pre(const float* __restrict__ emb,
                                             const float* __restrict__ cw0,
                                             float* __restrict__ cm,
                                             float* __restrict__ s1,
                                             float* __restrict__ s2,
                                             float* __restrict__ accum,
                                             const int* __restrict__ item_seq,
                                             const float* __restrict__ W,
                                             ushort* __restrict__ hb16) {
  const int t = threadIdx.x;
  if (blockIdx.x < NHM) {
    __shared__ __align__(16) ushort sWf[32 * 512];   // W bf16 fragments, 32 KB
    const int w = t >> 6;
    const int lane = t & 63;
    const int lr = lane & 15;
    const int lq = lane >> 4;
    const int m0 = blockIdx.x * 128;

#pragma unroll
    for (int it = 0; it < 8; ++it) {
      int pos = t + it * 256;
      int ch = pos >> 6, l = pos & 63;
      int n = (ch & 7) * 16 + (l & 15);
      int k0 = (ch >> 3) * 32 + (l >> 4) * 8;
      float4 a = *(const float4*)&W[n * HH + k0];
      float4 b = *(const float4*)&W[n * HH + k0 + 4];
      *(bf16x8*)&sWf[ch * 512 + l * 8] = cvt8(a, b);
    }

    bf16x8 af[4][2];
#pragma unroll
    for (int vv = 0; vv < 2; ++vv) {
      int m = m0 + w * 32 + vv * 16 + lr;
      int idx = item_seq[m];
#pragma unroll
      for (int ks = 0; ks < 4; ++ks) {
        if (idx != 0) {
          float4 a = *(const float4*)&emb[(size_t)idx * HH + ks * 32 + lq * 8];
          float4 b = *(const float4*)&emb[(size_t)idx * HH + ks * 32 + lq * 8 + 4];
          af[ks][vv] = cvt8(a, b);
        } else {
          af[ks][vv] = (bf16x8){0, 0, 0, 0, 0, 0, 0, 0};
        }
      }
    }
    __syncthreads();

    f32x4 acc[8][2];
#pragma unroll
    for (int nt = 0; nt < 8; ++nt)
#pragma unroll
      for (int vv = 0; vv < 2; ++vv) acc[nt][vv] = (f32x4){0.f, 0.f, 0.f, 0.f};

#pragma unroll
    for (int ks = 0; ks < 4; ++ks) {
      bf16x8 bw[8];
#pragma unroll
      for (int nt = 0; nt < 8; ++nt)
        bw[nt] = *(const bf16x8*)&sWf[(ks * 8 + nt) * 512 + lane * 8];
#pragma unroll
      for (int nt = 0; nt < 8; ++nt)
#pragma unroll
        for (int vv = 0; vv < 2; ++vv)
          acc[nt][vv] = __builtin_amdgcn_mfma_f32_16x16x32_bf16(af[ks][vv], bw[nt], acc[nt][vv], 0, 0, 0);
    }

#pragma unroll
    for (int nt = 0; nt < 8; ++nt)
#pragma unroll
      for (int vv = 0; vv < 2; ++vv)
#pragma unroll
        for (int r = 0; r < 4; ++r) {
          int m = m0 + w * 32 + vv * 16 + lq * 4 + r;
          hb16[(size_t)m * HH + nt * 16 + lr] = f2bf(acc[nt][vv][r]);
        }
  } else {
    __shared__ float red[256];
    const int c = blockIdx.x - NHM;
    if (t < 8) s1[t * KS + c] = 0.f;
    if (t >= 8 && t < 16) s2[(t - 8) * KS + c] = 0.f;
    if (c < 4) accum[c * 256 + t] = 0.f;
    float s = 0.f;
    for (int b = t; b < BB; b += 256) s += __expf(cw0[(size_t)b * KS + c]);
    red[t] = s;
    __syncthreads();
    for (int o = 128; o > 0; o >>= 1) {
      if (t < o) red[t] += red[t + o];
      __syncthreads();
    }
    if (t == 0) cm[c] = red[0];
  }
}

// ---- all 3 routing iterations: ONE COOPERATIVE kernel --------------------
// 1024 blocks, residency GUARANTEED by hipLaunchCooperativeKernel (the R8
// spin-barrier failure mode was non-resident blocks being preempted).
// h staged to LDS once; cw lives in LDS across iterations (zero global cw
// traffic); column exp-sums exchanged via 8-slot atomics + grid.sync().
__global__ __launch_bounds__(256) void k_route_all(const float* __restrict__ cw0,
                                                   const ushort* __restrict__ hb16,
                                                   const float* __restrict__ cm,
                                                   float* __restrict__ s1,
                                                   float* __restrict__ s2,
                                                   const float* __restrict__ mask,
                                                   float* __restrict__ out_ue,
                                                   const float* __restrict__ emb,
                                                   const int* __restrict__ item,
                                                   ushort* __restrict__ bestb,
                                                   float* __restrict__ si) {
  cg::grid_group grid = cg::this_grid();
  __shared__ ushort shT[128 * SSP];   // [col][s] transposed h, 13 KB
  __shared__ float cwl[KS];
  __shared__ float swl[KS];
  __shared__ float maskl[SS];
  __shared__ float c32p[256];
  __shared__ float c32[128];
  __shared__ float csq[128];
  __shared__ float ie4r[32];
  __shared__ float ie4z[32];
  __shared__ float fac[4];
  __shared__ float cosk[4];
  __shared__ float cosr[4];
  __shared__ int kb;
  const int t = threadIdx.x;
  const int b = blockIdx.x;

  // stage h-slice transposed (ushort4 global loads, scalar LDS writes)
  for (int p = t; p < (SS * HH) / 4; p += 256) {
    int flat = 4 * p;
    int s = flat >> 7, col = flat & 127;
    ushort4 v = *(const ushort4*)&hb16[(size_t)b * SS * HH + flat];
    shT[(col + 0) * SSP + s] = v.x;
    shT[(col + 1) * SSP + s] = v.y;
    shT[(col + 2) * SSP + s] = v.z;
    shT[(col + 3) * SSP + s] = v.w;
  }
  if (t < KS) cwl[t] = cw0[(size_t)b * KS + t];
  if (t < SS) maskl[t] = mask[b * SS + t];
  __syncthreads();

  for (int iter = 0; iter < 3; ++iter) {
    if (t < KS) {
      float den;
      if (iter == 0) {
        den = cm[t];
      } else {
        const float* sb = (iter == 1) ? s1 : s2;
        den = 0.f;
#pragma unroll
        for (int g = 0; g < 8; ++g) den += sb[g * KS + t];
      }
      float v = __expf(cwl[t]) / den;
      if (maskl[t % SS] == 0.0f) v = 0.0f;
      swl[t] = v;
    }
    __syncthreads();

    {  // c32: col = t&127, s-half = t>>7 (25 each)
      int col = t & 127;
      int half = t >> 7;
      int k = col >> 5;
      float acc = 0.f;
      const float* swk = &swl[k * SS + half * 25];
      const ushort* hc = &shT[col * SSP + half * 25];
      for (int s = 0; s < 25; ++s) acc += swk[s] * bf2f(hc[s]);
      c32p[t] = acc;
    }
    __syncthreads();
    if (t < 128) c32[t] = c32p[t] + c32p[t + 128];
    __syncthreads();
    if (t < 4) {
      float nrm = 0.f;
#pragma unroll
      for (int j = 0; j < 32; ++j) { float c = c32[32 * t + j]; nrm += c * c; }
      nrm *= 4.0f;
      fac[t] = nrm / (1.0f + nrm) / sqrtf(nrm + 1e-9f);
    }
    __syncthreads();
    if (t < 128) csq[t] = c32[t] * fac[t >> 5];
    __syncthreads();

    if (iter < 2) {
      if (t < KS) {
        int k = t / SS, s = t % SS;
        const float* cq = &csq[32 * k];
        float d = 0.f;
#pragma unroll
        for (int j = 0; j < 32; ++j) d += bf2f(shT[(32 * k + j) * SSP + s]) * cq[j];
        float nv = cwl[t] + 4.0f * d;
        cwl[t] = nv;
        float* dst = (iter == 0) ? s1 : s2;
        atomicAdd(&dst[(b & 7) * KS + t], __expf(nv));
      }
      grid.sync();
    } else {
      for (int hh = t; hh < 512; hh += 256) {
        int k = hh >> 7, r = (hh & 127) >> 2;
        out_ue[(size_t)b * 512 + hh] = csq[32 * k + r];
      }
      if (t < 32) {
        int idx = item[b];
        const float* e = emb + (size_t)idx * HH + 4 * t;
        float v = e[0] + e[1] + e[2] + e[3];   // raw emb row (scores use raw emb)
        ie4r[t] = v;
        ie4z[t] = (idx == 0) ? 0.f : v;        // zeroed lookup (cos path)
      }
      __syncthreads();
      if (t < 4) {
        float cz = 0.f, cr = 0.f;
#pragma unroll
        for (int j = 0; j < 32; ++j) {
          cz += csq[32 * t + j] * ie4z[j];
          cr += csq[32 * t + j] * ie4r[j];
        }
        cosk[t] = cz; cosr[t] = cr;
      }
      __syncthreads();
      if (t == 0) {
        int kbest = 0; float bv = cosk[0];
#pragma unroll
        for (int k = 1; k < 4; ++k) if (cosk[k] > bv) { bv = cosk[k]; kbest = k; }
        kb = kbest;
        si[b] = cosr[kbest];
      }
      __syncthreads();
      if (t < 128) bestb[(size_t)b * HH + t] = f2bf(csq[32 * kb + (t >> 2)]);
    }
  }
}

// ---------------- scoring: MFMA bf16 GEMM + fused sum-of-exp --------------
// EXACT R6 tile (128v x 128b, 57 us measured; R7/R9/R11 perturbations all
// regressed — do not change the geometry). Atomic-accum epilogue.
__global__ __launch_bounds__(256) void k_score_mfma(const ushort* __restrict__ bestb,
                                                    const ushort* __restrict__ embb,
                                                    float* __restrict__ accum) {
  const int lin = blockIdx.x;
  const int xcd = lin & 7;
  const int g = lin >> 3;
  const int bt8 = g & 7;
  const int vt = xcd * (NVT8 / 8) + (g >> 3);
  if (vt >= NVT) return;   // uniform across block: safe

  __shared__ __align__(16) ushort sB[32 * 512];   // 32 KB
  __shared__ float ssm[128][4];
  const int t = threadIdx.x;
  const int w = t >> 6;
  const int lane = t & 63;
  const int lr = lane & 15;
  const int lq = lane >> 4;
  const int b0 = bt8 * 128;
  const int v0 = vt * 128 + w * 32;

  // emb fragments (per-wave unique), hoisted: 32 VGPRs in flight
  bf16x8 af[4][2];
#pragma unroll
  for (int ks = 0; ks < 4; ++ks)
#pragma unroll
    for (int vv = 0; vv < 2; ++vv)
      af[ks][vv] = *(const bf16x8*)&embb[(size_t)(v0 + vv * 16 + lr) * HH + ks * 32 + lq * 8];

  // stage bestb strip (fragment order: chunk ks*8+bt = 64 lanes x 16 B)
#pragma unroll
  for (int it = 0; it < 8; ++it) {
    int pos = t + it * 256;
    int ch = pos >> 6;
    int l = pos & 63;
    int ks = ch >> 3, bt = ch & 7;
    *(bf16x8*)&sB[ch * 512 + l * 8] =
        *(const bf16x8*)&bestb[(size_t)(b0 + bt * 16 + (l & 15)) * HH + ks * 32 + (l >> 4) * 8];
  }

  f32x4 acc[8][2];
#pragma unroll
  for (int bt = 0; bt < 8; ++bt)
#pragma unroll
    for (int vv = 0; vv < 2; ++vv) acc[bt][vv] = (f32x4){0.f, 0.f, 0.f, 0.f};

  __syncthreads();

  bf16x8 bcur[8];
#pragma unroll
  for (int bt = 0; bt < 8; ++bt)
    bcur[bt] = *(const bf16x8*)&sB[bt * 512 + lane * 8];

#pragma unroll
  for (int ks = 0; ks < 4; ++ks) {
    bf16x8 bnxt[8];
    if (ks < 3) {
#pragma unroll
      for (int bt = 0; bt < 8; ++bt)
        bnxt[bt] = *(const bf16x8*)&sB[((ks + 1) * 8 + bt) * 512 + lane * 8];
    }
#pragma unroll
    for (int bt = 0; bt < 8; ++bt)
#pragma unroll
      for (int vv = 0; vv < 2; ++vv)
        acc[bt][vv] = __builtin_amdgcn_mfma_f32_16x16x32_bf16(af[ks][vv], bcur[bt], acc[bt][vv], 0, 0, 0);
    if (ks < 3) {
#pragma unroll
      for (int bt = 0; bt < 8; ++bt) bcur[bt] = bnxt[bt];
    }
  }

  // epilogue: plain sum-of-exp per b column (no max: |score| <~ 0.5)
#pragma unroll
  for (int bt = 0; bt < 8; ++bt) {
    float s = 0.f;
#pragma unroll
    for (int vv = 0; vv < 2; ++vv)
#pragma unroll
      for (int r = 0; r < 4; ++r) s += __expf(acc[bt][vv][r]);
    s += __shfl_xor(s, 16);
    s += __shfl_xor(s, 32);
    if (lq == 0) ssm[bt * 16 + lr][w] = s;
  }
  __syncthreads();
  if (t < 128) {
    float s = ssm[t][0] + ssm[t][1] + ssm[t][2] + ssm[t][3];
    atomicAdd(&accum[b0 + t], s);
  }
}

// ---------------- final loss: one block -----------------------------------
__global__ __launch_bounds__(256) void k_loss(const float* __restrict__ accum,
                                              const float* __restrict__ si,
                                              float* __restrict__ outloss) {
  __shared__ float red[256];
  const int t = threadIdx.x;
  float s = 0.f;
  for (int b = t; b < BB; b += 256)
    s += logf(accum[b] - NPAD_LAST) - si[b];   // no max: scores ~[-0.5,0.5]
  red[t] = s;
  __syncthreads();
  for (int o = 128; o > 0; o >>= 1) {
    if (t < o) red[t] += red[t + o];
    __syncthreads();
  }
  if (t == 0) outloss[0] = red[0] / (float)BB;
}

extern "C" void kernel_launch(void* const* d_in, const int* in_sizes, int n_in,
                              void* d_out, int out_size, void* d_ws, size_t ws_size,
                              hipStream_t stream) {
  const int*   item_seq = (const int*)d_in[0];
  const float* mask     = (const float*)d_in[1];
  const int*   item     = (const int*)d_in[2];
  const float* emb      = (const float*)d_in[3];
  const float* W        = (const float*)d_in[4];
  const float* cw0      = (const float*)d_in[5];
  float* out = (float*)d_out;
  float* outloss = out + (size_t)BB * KK * HH;

  float* ws = (float*)d_ws;
  float* cm    = ws;                                 // KS (rounded 256)
  float* s1    = cm + 256;                           // 8*200
  float* s2    = s1 + 8 * KS;                        // 8*200
  float* si    = s2 + 8 * KS;                        // B
  float* accum = si + BB;                            // B
  ushort* hb16  = (ushort*)(accum + BB);             // B*S*H bf16
  ushort* embb  = hb16 + (size_t)BB * SS * HH;       // VPAD*H bf16
  ushort* bestb = embb + (size_t)VPAD * HH;          // B*H bf16

  k_pre<<<dim3(NHM + KS), 256, 0, stream>>>(emb, cw0, cm, s1, s2, accum,
                                            item_seq, W, hb16);
  k_conv<<<dim3((VPAD * HH) / 1024), 256, 0, stream>>>(emb, embb);

  {
    const ushort* hb16c = hb16;
    void* args[] = {(void*)&cw0, (void*)&hb16c, (void*)&cm, (void*)&s1,
                    (void*)&s2, (void*)&mask, (void*)&out, (void*)&emb,
                    (void*)&item, (void*)&bestb, (void*)&si};
    hipLaunchCooperativeKernel((void*)k_route_all, dim3(BB), dim3(256),
                               args, 0, stream);
  }

  k_score_mfma<<<dim3(NVT8 * 8), 256, 0, stream>>>(bestb, embb, accum);
  k_loss<<<dim3(1), 256, 0, stream>>>(accum, si, outloss);
}

// Round 13
// 199.682 us; speedup vs baseline: 2.1006x; 2.1006x over previous
//
#include <hip/hip_runtime.h>
#include <math.h>

#define BB 1024
#define SS 50
#define SSP 51          // padded LDS row stride for shT
#define HH 128
#define KK 4
#define VV 100000
#define NVT 782         // ceil(V/128)
#define NVT8 784        // padded to multiple of 8 for XCD swizzle
#define VPAD (NVT8*128) // 100352 zero-padded emb rows
#define KS (KK*SS)      // 200
#define NHM 400         // h-MFMA blocks (128 rows each)
#define NPAD_LAST 96.0f // pad rows in tile 781, each contributes exp(0)=1

typedef __attribute__((ext_vector_type(8))) short bf16x8;
typedef __attribute__((ext_vector_type(4))) float f32x4;

__device__ __forceinline__ ushort f2bf(float x) {
  unsigned u = __float_as_uint(x);
  unsigned r = u + 0x7FFF + ((u >> 16) & 1);   // round-to-nearest-even
  return (ushort)(r >> 16);
}
__device__ __forceinline__ float bf2f(ushort u) {
  return __uint_as_float(((unsigned)u) << 16);
}
__device__ __forceinline__ bf16x8 cvt8(float4 a, float4 b) {
  bf16x8 r;
  r[0] = (short)f2bf(a.x); r[1] = (short)f2bf(a.y);
  r[2] = (short)f2bf(a.z); r[3] = (short)f2bf(a.w);
  r[4] = (short)f2bf(b.x); r[5] = (short)f2bf(b.y);
  r[6] = (short)f2bf(b.z); r[7] = (short)f2bf(b.w);
  return r;
}

// ---- standalone emb -> bf16 conversion (ZERO LDS -> full occupancy BW) ---
__global__ __launch_bounds__(256) void k_conv(const float* __restrict__ emb,
                                              ushort* __restrict__ embb) {
  size_t i = ((size_t)blockIdx.x * 256 + threadIdx.x) * 4;
  ushort4 o;
  if (i < (size_t)VV * HH) {
    float4 v = *(const float4*)&emb[i];
    o = make_ushort4(f2bf(v.x), f2bf(v.y), f2bf(v.z), f2bf(v.w));
  } else {
    o = make_ushort4(0, 0, 0, 0);
  }
  *(ushort4*)&embb[i] = o;
}

// ---- fused pre-pass ------------------------------------------------------
// blocks [0,NHM): h = seq_emb @ W^T via bf16 MFMA -> hb16
// blocks [NHM,NHM+KS): cw0 column exp-sums + zero s1/s2/accum
__global__ __launch_bounds__(256) void k_pre(const float* __restrict__ emb,
                                             const float* __restrict__ cw0,
                                             float* __restrict__ cm,
                                             float* __restrict__ s1,
                                             float* __restrict__ s2,
                                             float* __restrict__ accum,
                                             const int* __restrict__ item_seq,
                                             const float* __restrict__ W,
                                             ushort* __restrict__ hb16) {
  const int t = threadIdx.x;
  if (blockIdx.x < NHM) {
    __shared__ __align__(16) ushort sWf[32 * 512];   // W bf16 fragments, 32 KB
    const int w = t >> 6;
    const int lane = t & 63;
    const int lr = lane & 15;
    const int lq = lane >> 4;
    const int m0 = blockIdx.x * 128;

#pragma unroll
    for (int it = 0; it < 8; ++it) {
      int pos = t + it * 256;
      int ch = pos >> 6, l = pos & 63;
      int n = (ch & 7) * 16 + (l & 15);
      int k0 = (ch >> 3) * 32 + (l >> 4) * 8;
      float4 a = *(const float4*)&W[n * HH + k0];
      float4 b = *(const float4*)&W[n * HH + k0 + 4];
      *(bf16x8*)&sWf[ch * 512 + l * 8] = cvt8(a, b);
    }

    bf16x8 af[4][2];
#pragma unroll
    for (int vv = 0; vv < 2; ++vv) {
      int m = m0 + w * 32 + vv * 16 + lr;
      int idx = item_seq[m];
#pragma unroll
      for (int ks = 0; ks < 4; ++ks) {
        if (idx != 0) {
          float4 a = *(const float4*)&emb[(size_t)idx * HH + ks * 32 + lq * 8];
          float4 b = *(const float4*)&emb[(size_t)idx * HH + ks * 32 + lq * 8 + 4];
          af[ks][vv] = cvt8(a, b);
        } else {
          af[ks][vv] = (bf16x8){0, 0, 0, 0, 0, 0, 0, 0};
        }
      }
    }
    __syncthreads();

    f32x4 acc[8][2];
#pragma unroll
    for (int nt = 0; nt < 8; ++nt)
#pragma unroll
      for (int vv = 0; vv < 2; ++vv) acc[nt][vv] = (f32x4){0.f, 0.f, 0.f, 0.f};

#pragma unroll
    for (int ks = 0; ks < 4; ++ks) {
      bf16x8 bw[8];
#pragma unroll
      for (int nt = 0; nt < 8; ++nt)
        bw[nt] = *(const bf16x8*)&sWf[(ks * 8 + nt) * 512 + lane * 8];
#pragma unroll
      for (int nt = 0; nt < 8; ++nt)
#pragma unroll
        for (int vv = 0; vv < 2; ++vv)
          acc[nt][vv] = __builtin_amdgcn_mfma_f32_16x16x32_bf16(af[ks][vv], bw[nt], acc[nt][vv], 0, 0, 0);
    }

#pragma unroll
    for (int nt = 0; nt < 8; ++nt)
#pragma unroll
      for (int vv = 0; vv < 2; ++vv)
#pragma unroll
        for (int r = 0; r < 4; ++r) {
          int m = m0 + w * 32 + vv * 16 + lq * 4 + r;
          hb16[(size_t)m * HH + nt * 16 + lr] = f2bf(acc[nt][vv][r]);
        }
  } else {
    __shared__ float red[256];
    const int c = blockIdx.x - NHM;
    if (t < 8) s1[t * KS + c] = 0.f;
    if (t >= 8 && t < 16) s2[(t - 8) * KS + c] = 0.f;
    if (c < 4) accum[c * 256 + t] = 0.f;
    float s = 0.f;
    for (int b = t; b < BB; b += 256) s += __expf(cw0[(size_t)b * KS + c]);
    red[t] = s;
    __syncthreads();
    for (int o = 128; o > 0; o >>= 1) {
      if (t < o) red[t] += red[t + o];
      __syncthreads();
    }
    if (t == 0) cm[c] = red[0];
  }
}

// ---------------- routing: per-batch step (h LDS-staged, bf16) ------------
// 3 separate launches — the launch boundary IS the grid barrier. (R8 spin
// barrier and R12 cooperative grid.sync both measured ~227 us at ~2% VALU:
// grid-wide sync inside a kernel is ~100x more expensive than a launch.)
__global__ __launch_bounds__(256) void k_route(const float* __restrict__ cwsrc,
                                               float* __restrict__ cwdst,
                                               const ushort* __restrict__ hb16,
                                               const float* __restrict__ csum,
                                               int nslots,
                                               const float* __restrict__ mask,
                                               int last,
                                               float* __restrict__ out_ue,
                                               const float* __restrict__ emb,
                                               const int* __restrict__ item,
                                               ushort* __restrict__ bestb,
                                               float* __restrict__ csnext,
                                               float* __restrict__ si) {
  __shared__ ushort shT[128 * SSP];   // [col][s] transposed h, 13 KB
  __shared__ float swl[KS];
  __shared__ float c32p[256];
  __shared__ float c32[128];
  __shared__ float csq[128];
  __shared__ float ie4r[32];
  __shared__ float ie4z[32];
  __shared__ float fac[4];
  __shared__ float cosk[4];
  __shared__ float cosr[4];
  __shared__ int kb;
  const int t = threadIdx.x;
  const int b = blockIdx.x;

  for (int p = t; p < (SS * HH) / 4; p += 256) {
    int flat = 4 * p;
    int s = flat >> 7, col = flat & 127;
    ushort4 v = *(const ushort4*)&hb16[(size_t)b * SS * HH + flat];
    shT[(col + 0) * SSP + s] = v.x;
    shT[(col + 1) * SSP + s] = v.y;
    shT[(col + 2) * SSP + s] = v.z;
    shT[(col + 3) * SSP + s] = v.w;
  }
  if (t < KS) {
    float den = 0.f;
    for (int g2 = 0; g2 < nslots; ++g2) den += csum[g2 * KS + t];
    float v = __expf(cwsrc[(size_t)b * KS + t]) / den;
    if (mask[b * SS + (t % SS)] == 0.0f) v = 0.0f;
    swl[t] = v;
  }
  __syncthreads();

  {  // c32: col = t&127, s-half = t>>7 (25 each)
    int col = t & 127;
    int half = t >> 7;
    int k = col >> 5;
    float acc = 0.f;
    const float* swk = &swl[k * SS + half * 25];
    const ushort* hc = &shT[col * SSP + half * 25];
    for (int s = 0; s < 25; ++s) acc += swk[s] * bf2f(hc[s]);
    c32p[t] = acc;
  }
  __syncthreads();
  if (t < 128) c32[t] = c32p[t] + c32p[t + 128];
  __syncthreads();
  if (t < 4) {
    float nrm = 0.f;
#pragma unroll
    for (int j = 0; j < 32; ++j) { float c = c32[32 * t + j]; nrm += c * c; }
    nrm *= 4.0f;
    fac[t] = nrm / (1.0f + nrm) / sqrtf(nrm + 1e-9f);
  }
  __syncthreads();
  if (t < 128) csq[t] = c32[t] * fac[t >> 5];
  __syncthreads();

  if (!last) {
    if (t < KS) {
      int k = t / SS, s = t % SS;
      const float* cq = &csq[32 * k];
      float d = 0.f;
#pragma unroll
      for (int j = 0; j < 32; ++j) d += bf2f(shT[(32 * k + j) * SSP + s]) * cq[j];
      float nv = cwsrc[(size_t)b * KS + t] + 4.0f * d;
      cwdst[(size_t)b * KS + t] = nv;
      atomicAdd(&csnext[(b & 7) * KS + t], __expf(nv));
    }
  } else {
    for (int hh = t; hh < 512; hh += 256) {
      int k = hh >> 7, r = (hh & 127) >> 2;
      out_ue[(size_t)b * 512 + hh] = csq[32 * k + r];
    }
    if (t < 32) {
      int idx = item[b];
      const float* e = emb + (size_t)idx * HH + 4 * t;
      float v = e[0] + e[1] + e[2] + e[3];   // raw emb row (scores use raw emb)
      ie4r[t] = v;
      ie4z[t] = (idx == 0) ? 0.f : v;        // zeroed lookup (cos path)
    }
    __syncthreads();
    if (t < 4) {
      float cz = 0.f, cr = 0.f;
#pragma unroll
      for (int j = 0; j < 32; ++j) {
        cz += csq[32 * t + j] * ie4z[j];
        cr += csq[32 * t + j] * ie4r[j];
      }
      cosk[t] = cz; cosr[t] = cr;
    }
    __syncthreads();
    if (t == 0) {
      int kbest = 0; float bv = cosk[0];
#pragma unroll
      for (int k = 1; k < 4; ++k) if (cosk[k] > bv) { bv = cosk[k]; kbest = k; }
      kb = kbest;
      si[b] = cosr[kbest];
    }
    __syncthreads();
    if (t < 128) bestb[(size_t)b * HH + t] = f2bf(csq[32 * kb + (t >> 2)]);
  }
}

// ---------------- scoring: MFMA bf16 GEMM + fused sum-of-exp --------------
// EXACT R6 tile (128v x 128b, 57 us measured; R7/R9/R11 perturbations all
// regressed — geometry is pinned). Atomic-accum epilogue (no ps buffer).
__global__ __launch_bounds__(256) void k_score_mfma(const ushort* __restrict__ bestb,
                                                    const ushort* __restrict__ embb,
                                                    float* __restrict__ accum) {
  const int lin = blockIdx.x;
  const int xcd = lin & 7;
  const int g = lin >> 3;
  const int bt8 = g & 7;
  const int vt = xcd * (NVT8 / 8) + (g >> 3);
  if (vt >= NVT) return;   // uniform across block: safe

  __shared__ __align__(16) ushort sB[32 * 512];   // 32 KB
  __shared__ float ssm[128][4];
  const int t = threadIdx.x;
  const int w = t >> 6;
  const int lane = t & 63;
  const int lr = lane & 15;
  const int lq = lane >> 4;
  const int b0 = bt8 * 128;
  const int v0 = vt * 128 + w * 32;

  // emb fragments (per-wave unique), hoisted: 32 VGPRs in flight
  bf16x8 af[4][2];
#pragma unroll
  for (int ks = 0; ks < 4; ++ks)
#pragma unroll
    for (int vv = 0; vv < 2; ++vv)
      af[ks][vv] = *(const bf16x8*)&embb[(size_t)(v0 + vv * 16 + lr) * HH + ks * 32 + lq * 8];

  // stage bestb strip (fragment order: chunk ks*8+bt = 64 lanes x 16 B)
#pragma unroll
  for (int it = 0; it < 8; ++it) {
    int pos = t + it * 256;
    int ch = pos >> 6;
    int l = pos & 63;
    int ks = ch >> 3, bt = ch & 7;
    *(bf16x8*)&sB[ch * 512 + l * 8] =
        *(const bf16x8*)&bestb[(size_t)(b0 + bt * 16 + (l & 15)) * HH + ks * 32 + (l >> 4) * 8];
  }

  f32x4 acc[8][2];
#pragma unroll
  for (int bt = 0; bt < 8; ++bt)
#pragma unroll
    for (int vv = 0; vv < 2; ++vv) acc[bt][vv] = (f32x4){0.f, 0.f, 0.f, 0.f};

  __syncthreads();

  bf16x8 bcur[8];
#pragma unroll
  for (int bt = 0; bt < 8; ++bt)
    bcur[bt] = *(const bf16x8*)&sB[bt * 512 + lane * 8];

#pragma unroll
  for (int ks = 0; ks < 4; ++ks) {
    bf16x8 bnxt[8];
    if (ks < 3) {
#pragma unroll
      for (int bt = 0; bt < 8; ++bt)
        bnxt[bt] = *(const bf16x8*)&sB[((ks + 1) * 8 + bt) * 512 + lane * 8];
    }
#pragma unroll
    for (int bt = 0; bt < 8; ++bt)
#pragma unroll
      for (int vv = 0; vv < 2; ++vv)
        acc[bt][vv] = __builtin_amdgcn_mfma_f32_16x16x32_bf16(af[ks][vv], bcur[bt], acc[bt][vv], 0, 0, 0);
    if (ks < 3) {
#pragma unroll
      for (int bt = 0; bt < 8; ++bt) bcur[bt] = bnxt[bt];
    }
  }

  // epilogue: plain sum-of-exp per b column (no max: |score| <~ 0.5)
#pragma unroll
  for (int bt = 0; bt < 8; ++bt) {
    float s = 0.f;
#pragma unroll
    for (int vv = 0; vv < 2; ++vv)
#pragma unroll
      for (int r = 0; r < 4; ++r) s += __expf(acc[bt][vv][r]);
    s += __shfl_xor(s, 16);
    s += __shfl_xor(s, 32);
    if (lq == 0) ssm[bt * 16 + lr][w] = s;
  }
  __syncthreads();
  if (t < 128) {
    float s = ssm[t][0] + ssm[t][1] + ssm[t][2] + ssm[t][3];
    atomicAdd(&accum[b0 + t], s);
  }
}

// ---------------- final loss: one block -----------------------------------
__global__ __launch_bounds__(256) void k_loss(const float* __restrict__ accum,
                                              const float* __restrict__ si,
                                              float* __restrict__ outloss) {
  __shared__ float red[256];
  const int t = threadIdx.x;
  float s = 0.f;
  for (int b = t; b < BB; b += 256)
    s += logf(accum[b] - NPAD_LAST) - si[b];   // no max: scores ~[-0.5,0.5]
  red[t] = s;
  __syncthreads();
  for (int o = 128; o > 0; o >>= 1) {
    if (t < o) red[t] += red[t + o];
    __syncthreads();
  }
  if (t == 0) outloss[0] = red[0] / (float)BB;
}

extern "C" void kernel_launch(void* const* d_in, const int* in_sizes, int n_in,
                              void* d_out, int out_size, void* d_ws, size_t ws_size,
                              hipStream_t stream) {
  const int*   item_seq = (const int*)d_in[0];
  const float* mask     = (const float*)d_in[1];
  const int*   item     = (const int*)d_in[2];
  const float* emb      = (const float*)d_in[3];
  const float* W        = (const float*)d_in[4];
  const float* cw0      = (const float*)d_in[5];
  float* out = (float*)d_out;
  float* outloss = out + (size_t)BB * KK * HH;

  float* ws = (float*)d_ws;
  float* cm    = ws;                                 // KS (rounded 256)
  float* s1    = cm + 256;                           // 8*200
  float* s2    = s1 + 8 * KS;                        // 8*200
  float* si    = s2 + 8 * KS;                        // B
  float* accum = si + BB;                            // B
  float* cw    = accum + BB;                         // B*K*S
  ushort* hb16  = (ushort*)(cw + (size_t)BB * KS);   // B*S*H bf16
  ushort* embb  = hb16 + (size_t)BB * SS * HH;       // VPAD*H bf16
  ushort* bestb = embb + (size_t)VPAD * HH;          // B*H bf16

  k_pre<<<dim3(NHM + KS), 256, 0, stream>>>(emb, cw0, cm, s1, s2, accum,
                                            item_seq, W, hb16);
  k_conv<<<dim3((VPAD * HH) / 1024), 256, 0, stream>>>(emb, embb);

  k_route<<<dim3(BB), 256, 0, stream>>>(cw0, cw, hb16, cm, 1, mask, 0, out, emb, item, bestb, s1, si);
  k_route<<<dim3(BB), 256, 0, stream>>>(cw, cw, hb16, s1, 8, mask, 0, out, emb, item, bestb, s2, si);
  k_route<<<dim3(BB), 256, 0, stream>>>(cw, cw, hb16, s2, 8, mask, 1, out, emb, item, bestb, s1, si);

  k_score_mfma<<<dim3(NVT8 * 8), 256, 0, stream>>>(bestb, embb, accum);
  k_loss<<<dim3(1), 256, 0, stream>>>(accum, si, outloss);
}